// Round 6
// baseline (275.405 us; speedup 1.0000x reference)
//
#include <hip/hip_runtime.h>

typedef unsigned short u16;
typedef unsigned int   u32;
typedef __bf16 bf16x8 __attribute__((ext_vector_type(8)));
typedef float  f32x4  __attribute__((ext_vector_type(4)));
typedef unsigned short u16x8 __attribute__((ext_vector_type(8)));
typedef unsigned short u16x4 __attribute__((ext_vector_type(4)));

#define SEQ 2048
#define DM  1024
#define TOKS 8388608  // 4*2048*1024 elements
#define SCLQ 0.18033688f  // log2(e)/8, folded into Q projection

__device__ __forceinline__ float bf2f(u16 u) {
    u32 i = ((u32)u) << 16;
    float f; __builtin_memcpy(&f, &i, 4); return f;
}
__device__ __forceinline__ u16 f2bf(float f) {
    u32 i; __builtin_memcpy(&i, &f, 4);
    return (u16)((i + 0x7FFFu + ((i >> 16) & 1u)) >> 16);  // RNE
}
__device__ __forceinline__ bf16x8 ld8(const u16* p) {
    return __builtin_bit_cast(bf16x8, *(const u16x8*)p);
}
#define GLD16(src, dst) __builtin_amdgcn_global_load_lds( \
    (const __attribute__((address_space(1))) void*)(src), \
    (__attribute__((address_space(3))) void*)(dst), 16, 0, 0)

// Wave-local dtype sniff: bf16 inputs -> both u16 halves of x words have sane
// exponents; fp32 inputs -> low half is mantissa garbage.
__device__ __forceinline__ int sniff_fp32(const u32* x) {
    u32 w = x[threadIdx.x & 63];
    int e0 = (int)((w >> 7) & 0xFFu);
    int cnt = (e0 >= 100 && e0 <= 140) ? 1 : 0;
#pragma unroll
    for (int off = 32; off; off >>= 1) cnt += __shfl_xor(cnt, off);
    return cnt < 32;   // 1 = fp32 inputs
}

// ---------------- prep: dtype-detect + (fp32-only) weight convert + LayerNorm ----
// grid.x: [0,8192) ln rows | [8192,12288) weight convert (fp32 mode only) | 12288 biases+flag
__global__ __launch_bounds__(256) void prep_k(const void* __restrict__ x,
                                              const void* Wq, const void* Wk, const void* Wv, const void* Wo,
                                              const void* bq, const void* bk, const void* bv, const void* bo,
                                              const void* g, const void* b,
                                              u16* __restrict__ dstW, u16* __restrict__ dstV,
                                              u16* __restrict__ xn, int* __restrict__ flagp) {
    const int bid = blockIdx.x, tid = threadIdx.x;
    const int fp32m = sniff_fp32((const u32*)x);

    if (bid < 8192) {
        const int row = bid;
        float f[4], s1 = 0.f, s2 = 0.f;
        if (fp32m) {
            f32x4 v = *(const f32x4*)((const float*)x + (size_t)row * DM + tid * 4);
#pragma unroll
            for (int j = 0; j < 4; ++j) f[j] = v[j];
        } else {
            u16x4 v = *(const u16x4*)((const u16*)x + (size_t)row * DM + tid * 4);
#pragma unroll
            for (int j = 0; j < 4; ++j) f[j] = bf2f(v[j]);
        }
#pragma unroll
        for (int j = 0; j < 4; ++j) { s1 += f[j]; s2 += f[j] * f[j]; }
#pragma unroll
        for (int off = 32; off; off >>= 1) { s1 += __shfl_xor(s1, off); s2 += __shfl_xor(s2, off); }
        __shared__ float red[8];
        const int wave = tid >> 6, lane = tid & 63;
        if (lane == 0) { red[wave] = s1; red[4 + wave] = s2; }
        __syncthreads();
        s1 = red[0] + red[1] + red[2] + red[3];
        s2 = red[4] + red[5] + red[6] + red[7];
        const float mu = s1 * (1.f / DM);
        const float var = s2 * (1.f / DM) - mu * mu;
        const float rs = rsqrtf(var + 1e-5f);
        float gv[4], bv2[4];
        if (fp32m) {
            f32x4 gg = *(const f32x4*)((const float*)g + tid * 4);
            f32x4 bb = *(const f32x4*)((const float*)b + tid * 4);
#pragma unroll
            for (int j = 0; j < 4; ++j) { gv[j] = gg[j]; bv2[j] = bb[j]; }
        } else {
            u16x4 gg = *(const u16x4*)((const u16*)g + tid * 4);
            u16x4 bb = *(const u16x4*)((const u16*)b + tid * 4);
#pragma unroll
            for (int j = 0; j < 4; ++j) { gv[j] = bf2f(gg[j]); bv2[j] = bf2f(bb[j]); }
        }
        u16x4 o;
#pragma unroll
        for (int j = 0; j < 4; ++j) o[j] = f2bf((f[j] - mu) * rs * gv[j] + bv2[j]);
        *(u16x4*)(xn + (size_t)row * DM + tid * 4) = o;
    } else if (bid < 12288) {
        if (!fp32m) return;   // bf16 mode: gemms read original pointers
        const int wi = (bid - 8192) >> 10, blk = (bid - 8192) & 1023;
        const void* src = (wi == 0) ? Wq : (wi == 1) ? Wk : (wi == 2) ? Wv : Wo;
        const size_t off = (size_t)blk * 1024 + tid * 4;
        const float* f = (const float*)src + off;
        u16x4 o;
#pragma unroll
        for (int j = 0; j < 4; ++j) o[j] = f2bf(f[j]);
        *(u16x4*)(dstW + (size_t)wi * 1048576 + off) = o;
    } else {
#pragma unroll
        for (int i = 0; i < 4; ++i) {
            const void* src = (i == 0) ? bq : (i == 1) ? bk : (i == 2) ? bv : bo;
            u16x4 o;
            if (fp32m) {
                const float* f = (const float*)src + tid * 4;
#pragma unroll
                for (int j = 0; j < 4; ++j) o[j] = f2bf(f[j]);
            } else {
                o = *(const u16x4*)((const u16*)src + tid * 4);
            }
            *(u16x4*)(dstV + (size_t)i * 1024 + tid * 4) = o;
        }
        if (tid == 0) *flagp = fp32m;
    }
}

// ---------------- QKV GEMM core (m97: 128x128, BK=32, global_load_lds w16) ----
template <int VT>
__device__ __forceinline__ void gemm_core(u16* As, u16* Bs,
                                          const u16* __restrict__ A,
                                          const u16* __restrict__ W,
                                          const u16* __restrict__ bias,
                                          u16* __restrict__ out,
                                          float scale) {
    const int tid = threadIdx.x, wave = tid >> 6, lane = tid & 63;
    const int l4 = lane & 15, q4 = lane >> 4;
    const int bm = blockIdx.x, bn = blockIdx.y;
    const int wm = (wave >> 1) * 64, wn = (wave & 1) * 64;
    f32x4 acc[4][4] = {};
    const int srow = wave * 32 + (lane >> 2);
    const int skoff = (lane & 3) * 8;
    const u16* Ag = A + ((size_t)(bm * 128 + srow)) * DM + skoff;
    const u16* Wg = W + ((size_t)(bn * 128 + srow)) * DM + skoff;
    u16* As0 = As + wave * 1024;
    u16* Bs0 = Bs + wave * 1024;

    for (int k0 = 0; k0 < DM; k0 += 32) {
        GLD16(Ag + k0, As0);
        GLD16(Ag + 16 * DM + k0, As0 + 512);
        GLD16(Wg + k0, Bs0);
        GLD16(Wg + 16 * DM + k0, Bs0 + 512);
        __syncthreads();
        bf16x8 af[4], bfr[4];
#pragma unroll
        for (int t = 0; t < 4; ++t)
            af[t] = ld8(As + (wm + t * 16 + l4) * 32 + q4 * 8);
#pragma unroll
        for (int t = 0; t < 4; ++t)
            bfr[t] = ld8(Bs + (wn + t * 16 + l4) * 32 + q4 * 8);
#pragma unroll
        for (int mt = 0; mt < 4; ++mt)
#pragma unroll
            for (int nt = 0; nt < 4; ++nt)
                acc[mt][nt] = __builtin_amdgcn_mfma_f32_16x16x32_bf16(af[mt], bfr[nt], acc[mt][nt], 0, 0, 0);
        __syncthreads();
    }

#pragma unroll
    for (int nt = 0; nt < 4; ++nt) {
        const int col = bn * 128 + wn + nt * 16 + l4;
        const float bs = bf2f(bias[col]);
#pragma unroll
        for (int mt = 0; mt < 4; ++mt) {
            const int row0 = bm * 128 + wm + mt * 16 + q4 * 4;
            if (VT == 1) {
                const int nb = row0 >> 11, s0 = row0 & 2047;
                u16x4 pk;
#pragma unroll
                for (int r = 0; r < 4; ++r) pk[r] = f2bf((acc[mt][nt][r] + bs) * scale);
                *(u16x4*)(out + ((size_t)(nb * 1024 + col)) * SEQ + s0) = pk;
            } else {
#pragma unroll
                for (int r = 0; r < 4; ++r)
                    out[(size_t)(row0 + r) * DM + col] = f2bf((acc[mt][nt][r] + bs) * scale);
            }
        }
    }
}

__global__ __launch_bounds__(256) void gemm_qkv_k(const u16* __restrict__ xn, const u16* __restrict__ Wc,
                                                  const u16* __restrict__ Vc,
                                                  const void* Wq, const void* Wk, const void* Wv,
                                                  const int* __restrict__ flagp,
                                                  u16* __restrict__ Q, u16* __restrict__ K, u16* __restrict__ Vt) {
    __shared__ alignas(16) u16 As[128 * 32];
    __shared__ alignas(16) u16 Bs[128 * 32];
    const int z = blockIdx.z;
    const int fp32m = *flagp;
    if (z == 0) {
        const u16* W = fp32m ? Wc : (const u16*)Wq;
        gemm_core<0>(As, Bs, xn, W, Vc, Q, SCLQ);
    } else if (z == 1) {
        const u16* W = fp32m ? (Wc + 1048576) : (const u16*)Wk;
        gemm_core<0>(As, Bs, xn, W, Vc + 1024, K, 1.0f);
    } else {
        const u16* W = fp32m ? (Wc + 2 * 1048576) : (const u16*)Wv;
        gemm_core<1>(As, Bs, xn, W, Vc + 2048, Vt, 1.0f);
    }
}

// ---------------- Output projection GEMM: 512-thread blocks (16 waves/CU) ----
__global__ __launch_bounds__(512) void gemm_out_k(const u16* __restrict__ Z, const u16* __restrict__ Wc,
                                                  const u16* __restrict__ Vc, const void* Wo,
                                                  u16* __restrict__ out, const int* __restrict__ flagp) {
    __shared__ alignas(16) u16 As[128 * 32];
    __shared__ alignas(16) u16 Bs[128 * 32];
    const int fp32m = *flagp;
    const u16* W = fp32m ? (Wc + 3 * 1048576) : (const u16*)Wo;
    const u16* bias = Vc + 3 * 1024;
    const int tid = threadIdx.x, wave = tid >> 6, lane = tid & 63;
    const int l4 = lane & 15, q4 = lane >> 4;
    const int bm = blockIdx.x, bn = blockIdx.y;
    const int wm = (wave >> 2) * 64, wn = (wave & 3) * 32;
    f32x4 acc[4][2] = {};
    const int srow = (wave & 3) * 32 + (lane >> 2);
    const int skoff = (lane & 3) * 8;
    const u16* Sg = (wave < 4) ? (Z + ((size_t)(bm * 128 + srow)) * DM + skoff)
                               : (W + ((size_t)(bn * 128 + srow)) * DM + skoff);
    u16* dst0 = (wave < 4) ? (As + (wave & 3) * 1024) : (Bs + (wave & 3) * 1024);

    for (int k0 = 0; k0 < DM; k0 += 32) {
        GLD16(Sg + k0, dst0);
        GLD16(Sg + 16 * DM + k0, dst0 + 512);
        __syncthreads();
        bf16x8 af[4], bfr[2];
#pragma unroll
        for (int t = 0; t < 4; ++t)
            af[t] = ld8(As + (wm + t * 16 + l4) * 32 + q4 * 8);
#pragma unroll
        for (int t = 0; t < 2; ++t)
            bfr[t] = ld8(Bs + (wn + t * 16 + l4) * 32 + q4 * 8);
#pragma unroll
        for (int mt = 0; mt < 4; ++mt)
#pragma unroll
            for (int nt = 0; nt < 2; ++nt)
                acc[mt][nt] = __builtin_amdgcn_mfma_f32_16x16x32_bf16(af[mt], bfr[nt], acc[mt][nt], 0, 0, 0);
        __syncthreads();
    }

#pragma unroll
    for (int nt = 0; nt < 2; ++nt) {
        const int col = bn * 128 + wn + nt * 16 + l4;
        const float bs = bf2f(bias[col]);
#pragma unroll
        for (int mt = 0; mt < 4; ++mt) {
            const int row0 = bm * 128 + wm + mt * 16 + q4 * 4;
            if (fp32m) {
#pragma unroll
                for (int r = 0; r < 4; ++r)
                    ((float*)out)[(size_t)(row0 + r) * DM + col] = acc[mt][nt][r] + bs;
            } else {
#pragma unroll
                for (int r = 0; r < 4; ++r)
                    out[(size_t)(row0 + r) * DM + col] = f2bf(acc[mt][nt][r] + bs);
            }
        }
    }
}

// ---------------- Flash attention: 64 q rows/wave, 256 q rows/block ----
// LDS-bound analysis: per wave-chunk 24 ds_read_b128 + 16 ds_write_b64 per 64
// MFMA (was 20+8 per 32). Per-qt wave-uniform causal skip avoids masked tiles.
// Grid (64,8): 512 blocks = 2/CU all-resident; y->qb mapped so (c, c+256)
// pairs get complementary chunk counts (36 uniform).
__global__ __launch_bounds__(256, 2) void flash_k(const u16* __restrict__ Q,
                                                  const u16* __restrict__ K,
                                                  const u16* __restrict__ Vt,
                                                  u16* __restrict__ Z) {
    const int bh = blockIdx.x;
    const int yy = (int)blockIdx.y;
    const int qb = (yy < 4) ? yy : 11 - yy;   // 0,1,2,3,7,6,5,4
    const int n = bh >> 4, h = bh & 15;
    const int tid = threadIdx.x, wave = tid >> 6, lane = tid & 63;
    const int l4 = lane & 15, q4 = lane >> 4;

    __shared__ alignas(16) u16 Ks[2][64 * 32];   // [k-half][kv][32 dm]
    __shared__ alignas(16) u16 Vs[2][64 * 32];   // [kv-half][d][32 kv]
    __shared__ alignas(16) u16 Pl[4][4][16 * 72];

    const int Q0w = qb * 256 + wave * 64;
    bf16x8 qf[4][2];
#pragma unroll
    for (int qt = 0; qt < 4; ++qt) {
        const u16* Qr = Q + ((size_t)(n * SEQ + Q0w + qt * 16 + l4)) * DM + h * 64 + q4 * 8;
        qf[qt][0] = ld8(Qr);
        qf[qt][1] = ld8(Qr + 32);
    }

    const int srow = lane >> 2, scol = (lane & 3) * 8;
    const u16* Kg = K + ((size_t)(n * SEQ + wave * 16 + srow)) * DM + h * 64 + scol;
    const u16* Vg = Vt + ((size_t)(n * 1024 + h * 64 + wave * 16 + srow)) * SEQ + scol;
    u16* KsD0 = &Ks[0][wave * 512];
    u16* KsD1 = &Ks[1][wave * 512];
    u16* VsD0 = &Vs[0][wave * 512];
    u16* VsD1 = &Vs[1][wave * 512];

    f32x4 o[4][4] = {};
    float l_acc[4] = {0.f, 0.f, 0.f, 0.f};
    const int nch = 4 * qb + 4;

    for (int c = 0; c < nch; ++c) {
        const int kv0 = c * 64;
        const size_t krow = (size_t)kv0 * DM;
        GLD16(Kg + krow, KsD0);
        GLD16(Kg + krow + 32, KsD1);
        GLD16(Vg + kv0, VsD0);
        GLD16(Vg + kv0 + 32, VsD1);
        __syncthreads();

        bf16x8 a[4][2];
#pragma unroll
        for (int mt = 0; mt < 4; ++mt) {
            a[mt][0] = ld8(&Ks[0][(mt * 16 + l4) * 32 + q4 * 8]);
            a[mt][1] = ld8(&Ks[1][(mt * 16 + l4) * 32 + q4 * 8]);
        }
#pragma unroll
        for (int qt = 0; qt < 4; ++qt) {
            const int qbase = Q0w + qt * 16;
            if (kv0 > qbase + 15) continue;   // fully masked tile: skip all
            f32x4 st[4];
#pragma unroll
            for (int mt = 0; mt < 4; ++mt) {
                f32x4 zz = {0.f, 0.f, 0.f, 0.f};
                st[mt] = __builtin_amdgcn_mfma_f32_16x16x32_bf16(a[mt][0], qf[qt][0], zz, 0, 0, 0);
                st[mt] = __builtin_amdgcn_mfma_f32_16x16x32_bf16(a[mt][1], qf[qt][1], st[mt], 0, 0, 0);
            }
            u16* P = Pl[wave][qt];
            float la = l_acc[qt];
            if (kv0 + 63 <= qbase) {
                // fully unmasked fast path
#pragma unroll
                for (int mt = 0; mt < 4; ++mt) {
                    __bf16 pk[4];
#pragma unroll
                    for (int r = 0; r < 4; ++r) {
                        float p = __builtin_amdgcn_exp2f(st[mt][r]);
                        la += p;
                        pk[r] = (__bf16)p;
                    }
                    *(u16x4*)(P + l4 * 72 + mt * 16 + q4 * 4) = *(u16x4*)pk;
                }
            } else {
                const int qg = qbase + l4;
#pragma unroll
                for (int mt = 0; mt < 4; ++mt) {
                    __bf16 pk[4];
#pragma unroll
                    for (int r = 0; r < 4; ++r) {
                        const int kv = kv0 + mt * 16 + q4 * 4 + r;
                        float p = __builtin_amdgcn_exp2f(st[mt][r]);
                        p = (kv > qg) ? 0.f : p;
                        la += p;
                        pk[r] = (__bf16)p;
                    }
                    *(u16x4*)(P + l4 * 72 + mt * 16 + q4 * 4) = *(u16x4*)pk;
                }
            }
            l_acc[qt] = la;
        }
        // O += P.V
#pragma unroll
        for (int ks = 0; ks < 2; ++ks) {
            bf16x8 vf[4];
#pragma unroll
            for (int nt = 0; nt < 4; ++nt)
                vf[nt] = ld8(&Vs[ks][(nt * 16 + l4) * 32 + q4 * 8]);
#pragma unroll
            for (int qt = 0; qt < 4; ++qt) {
                if (kv0 > Q0w + qt * 16 + 15) continue;
                bf16x8 pf = ld8(&Pl[wave][qt][l4 * 72 + ks * 32 + q4 * 8]);
#pragma unroll
                for (int nt = 0; nt < 4; ++nt)
                    o[qt][nt] = __builtin_amdgcn_mfma_f32_16x16x32_bf16(pf, vf[nt], o[qt][nt], 0, 0, 0);
            }
        }
        __syncthreads();
    }

#pragma unroll
    for (int qt = 0; qt < 4; ++qt) {
        float l = l_acc[qt];
        l += __shfl_xor(l, 16);
        l += __shfl_xor(l, 32);
        float lr[4];
#pragma unroll
        for (int r = 0; r < 4; ++r) lr[r] = 1.f / __shfl(l, q4 * 4 + r);
#pragma unroll
        for (int nt = 0; nt < 4; ++nt) {
            const int col = h * 64 + nt * 16 + l4;
#pragma unroll
            for (int r = 0; r < 4; ++r) {
                const int row = n * SEQ + Q0w + qt * 16 + q4 * 4 + r;
                Z[(size_t)row * DM + col] = f2bf(o[qt][nt][r] * lr[r]);
            }
        }
    }
}

extern "C" void kernel_launch(void* const* d_in, const int* in_sizes, int n_in,
                              void* d_out, int out_size, void* d_ws, size_t ws_size,
                              hipStream_t stream) {
    const void* x  = d_in[0];
    const void* Wq = d_in[1];
    const void* bq = d_in[2];
    const void* Wk = d_in[3];
    const void* bk = d_in[4];
    const void* Wv = d_in[5];
    const void* bv = d_in[6];
    const void* Wo = d_in[7];
    const void* bo = d_in[8];
    const void* g  = d_in[9];
    const void* b  = d_in[10];
    u16* ws = (u16*)d_ws;

    u16* xn  = ws;
    u16* Qb  = ws + (size_t)TOKS;
    u16* Kb  = ws + (size_t)2 * TOKS;
    u16* Vtb = ws + (size_t)3 * TOKS;
    u16* Zb  = ws;  // xn dead after qkv gemm
    u16* Wc  = ws + (size_t)4 * TOKS;
    u16* Vc  = Wc + 4 * 1048576;
    int* flagp = (int*)(Vc + 8 * 1024);

    prep_k<<<dim3(12289), 256, 0, stream>>>(x, Wq, Wk, Wv, Wo, bq, bk, bv, bo, g, b, Wc, Vc, xn, flagp);
    gemm_qkv_k<<<dim3(64, 8, 3), 256, 0, stream>>>(xn, Wc, Vc, Wq, Wk, Wv, flagp, Qb, Kb, Vtb);
    flash_k<<<dim3(64, 8), 256, 0, stream>>>(Qb, Kb, Vtb, Zb);
    gemm_out_k<<<dim3(64, 8), 512, 0, stream>>>(Zb, Wc, Vc, Wo, (u16*)d_out, flagp);
}

// Round 8
// 260.013 us; speedup vs baseline: 1.0592x; 1.0592x over previous
//
#include <hip/hip_runtime.h>

typedef unsigned short u16;
typedef unsigned int   u32;
typedef __bf16 bf16x8 __attribute__((ext_vector_type(8)));
typedef float  f32x4  __attribute__((ext_vector_type(4)));
typedef unsigned short u16x8 __attribute__((ext_vector_type(8)));
typedef unsigned short u16x4 __attribute__((ext_vector_type(4)));

#define SEQ 2048
#define DM  1024
#define TOKS 8388608  // 4*2048*1024 elements
#define SCLQ 0.18033688f  // log2(e)/8, folded into Q projection

__device__ __forceinline__ float bf2f(u16 u) {
    u32 i = ((u32)u) << 16;
    float f; __builtin_memcpy(&f, &i, 4); return f;
}
__device__ __forceinline__ u16 f2bf(float f) {
    u32 i; __builtin_memcpy(&i, &f, 4);
    return (u16)((i + 0x7FFFu + ((i >> 16) & 1u)) >> 16);  // RNE
}
__device__ __forceinline__ bf16x8 ld8(const u16* p) {
    return __builtin_bit_cast(bf16x8, *(const u16x8*)p);
}
#define GLD16(src, dst) __builtin_amdgcn_global_load_lds( \
    (const __attribute__((address_space(1))) void*)(src), \
    (__attribute__((address_space(3))) void*)(dst), 16, 0, 0)

// Wave-local dtype sniff: bf16 inputs -> both u16 halves of x words have sane
// exponents; fp32 inputs -> low half is mantissa garbage.
__device__ __forceinline__ int sniff_fp32(const u32* x) {
    u32 w = x[threadIdx.x & 63];
    int e0 = (int)((w >> 7) & 0xFFu);
    int cnt = (e0 >= 100 && e0 <= 140) ? 1 : 0;
#pragma unroll
    for (int off = 32; off; off >>= 1) cnt += __shfl_xor(cnt, off);
    return cnt < 32;   // 1 = fp32 inputs
}

// ---------------- prep: dtype-detect + (fp32-only) weight convert + LayerNorm ----
__global__ __launch_bounds__(256) void prep_k(const void* __restrict__ x,
                                              const void* Wq, const void* Wk, const void* Wv, const void* Wo,
                                              const void* bq, const void* bk, const void* bv, const void* bo,
                                              const void* g, const void* b,
                                              u16* __restrict__ dstW, u16* __restrict__ dstV,
                                              u16* __restrict__ xn, int* __restrict__ flagp) {
    const int bid = blockIdx.x, tid = threadIdx.x;
    const int fp32m = sniff_fp32((const u32*)x);

    if (bid < 8192) {
        const int row = bid;
        float f[4], s1 = 0.f, s2 = 0.f;
        if (fp32m) {
            f32x4 v = *(const f32x4*)((const float*)x + (size_t)row * DM + tid * 4);
#pragma unroll
            for (int j = 0; j < 4; ++j) f[j] = v[j];
        } else {
            u16x4 v = *(const u16x4*)((const u16*)x + (size_t)row * DM + tid * 4);
#pragma unroll
            for (int j = 0; j < 4; ++j) f[j] = bf2f(v[j]);
        }
#pragma unroll
        for (int j = 0; j < 4; ++j) { s1 += f[j]; s2 += f[j] * f[j]; }
#pragma unroll
        for (int off = 32; off; off >>= 1) { s1 += __shfl_xor(s1, off); s2 += __shfl_xor(s2, off); }
        __shared__ float red[8];
        const int wave = tid >> 6, lane = tid & 63;
        if (lane == 0) { red[wave] = s1; red[4 + wave] = s2; }
        __syncthreads();
        s1 = red[0] + red[1] + red[2] + red[3];
        s2 = red[4] + red[5] + red[6] + red[7];
        const float mu = s1 * (1.f / DM);
        const float var = s2 * (1.f / DM) - mu * mu;
        const float rs = rsqrtf(var + 1e-5f);
        float gv[4], bv2[4];
        if (fp32m) {
            f32x4 gg = *(const f32x4*)((const float*)g + tid * 4);
            f32x4 bb = *(const f32x4*)((const float*)b + tid * 4);
#pragma unroll
            for (int j = 0; j < 4; ++j) { gv[j] = gg[j]; bv2[j] = bb[j]; }
        } else {
            u16x4 gg = *(const u16x4*)((const u16*)g + tid * 4);
            u16x4 bb = *(const u16x4*)((const u16*)b + tid * 4);
#pragma unroll
            for (int j = 0; j < 4; ++j) { gv[j] = bf2f(gg[j]); bv2[j] = bf2f(bb[j]); }
        }
        u16x4 o;
#pragma unroll
        for (int j = 0; j < 4; ++j) o[j] = f2bf((f[j] - mu) * rs * gv[j] + bv2[j]);
        *(u16x4*)(xn + (size_t)row * DM + tid * 4) = o;
    } else if (bid < 12288) {
        if (!fp32m) return;   // bf16 mode: gemms read original pointers
        const int wi = (bid - 8192) >> 10, blk = (bid - 8192) & 1023;
        const void* src = (wi == 0) ? Wq : (wi == 1) ? Wk : (wi == 2) ? Wv : Wo;
        const size_t off = (size_t)blk * 1024 + tid * 4;
        const float* f = (const float*)src + off;
        u16x4 o;
#pragma unroll
        for (int j = 0; j < 4; ++j) o[j] = f2bf(f[j]);
        *(u16x4*)(dstW + (size_t)wi * 1048576 + off) = o;
    } else {
#pragma unroll
        for (int i = 0; i < 4; ++i) {
            const void* src = (i == 0) ? bq : (i == 1) ? bk : (i == 2) ? bv : bo;
            u16x4 o;
            if (fp32m) {
                const float* f = (const float*)src + tid * 4;
#pragma unroll
                for (int j = 0; j < 4; ++j) o[j] = f2bf(f[j]);
            } else {
                o = *(const u16x4*)((const u16*)src + tid * 4);
            }
            *(u16x4*)(dstV + (size_t)i * 1024 + tid * 4) = o;
        }
        if (tid == 0) *flagp = fp32m;
    }
}

// ---------------- QKV GEMM core (m97: 128x128, BK=32, global_load_lds w16) ----
template <int VT>
__device__ __forceinline__ void gemm_core(u16* As, u16* Bs,
                                          const u16* __restrict__ A,
                                          const u16* __restrict__ W,
                                          const u16* __restrict__ bias,
                                          u16* __restrict__ out,
                                          float scale) {
    const int tid = threadIdx.x, wave = tid >> 6, lane = tid & 63;
    const int l4 = lane & 15, q4 = lane >> 4;
    const int bm = blockIdx.x, bn = blockIdx.y;
    const int wm = (wave >> 1) * 64, wn = (wave & 1) * 64;
    f32x4 acc[4][4] = {};
    const int srow = wave * 32 + (lane >> 2);
    const int skoff = (lane & 3) * 8;
    const u16* Ag = A + ((size_t)(bm * 128 + srow)) * DM + skoff;
    const u16* Wg = W + ((size_t)(bn * 128 + srow)) * DM + skoff;
    u16* As0 = As + wave * 1024;
    u16* Bs0 = Bs + wave * 1024;

    for (int k0 = 0; k0 < DM; k0 += 32) {
        GLD16(Ag + k0, As0);
        GLD16(Ag + 16 * DM + k0, As0 + 512);
        GLD16(Wg + k0, Bs0);
        GLD16(Wg + 16 * DM + k0, Bs0 + 512);
        __syncthreads();
        bf16x8 af[4], bfr[4];
#pragma unroll
        for (int t = 0; t < 4; ++t)
            af[t] = ld8(As + (wm + t * 16 + l4) * 32 + q4 * 8);
#pragma unroll
        for (int t = 0; t < 4; ++t)
            bfr[t] = ld8(Bs + (wn + t * 16 + l4) * 32 + q4 * 8);
#pragma unroll
        for (int mt = 0; mt < 4; ++mt)
#pragma unroll
            for (int nt = 0; nt < 4; ++nt)
                acc[mt][nt] = __builtin_amdgcn_mfma_f32_16x16x32_bf16(af[mt], bfr[nt], acc[mt][nt], 0, 0, 0);
        __syncthreads();
    }

#pragma unroll
    for (int nt = 0; nt < 4; ++nt) {
        const int col = bn * 128 + wn + nt * 16 + l4;
        const float bs = bf2f(bias[col]);
#pragma unroll
        for (int mt = 0; mt < 4; ++mt) {
            const int row0 = bm * 128 + wm + mt * 16 + q4 * 4;
            if (VT == 1) {
                const int nb = row0 >> 11, s0 = row0 & 2047;
                u16x4 pk;
#pragma unroll
                for (int r = 0; r < 4; ++r) pk[r] = f2bf((acc[mt][nt][r] + bs) * scale);
                *(u16x4*)(out + ((size_t)(nb * 1024 + col)) * SEQ + s0) = pk;
            } else {
#pragma unroll
                for (int r = 0; r < 4; ++r)
                    out[(size_t)(row0 + r) * DM + col] = f2bf((acc[mt][nt][r] + bs) * scale);
            }
        }
    }
}

__global__ __launch_bounds__(256) void gemm_qkv_k(const u16* __restrict__ xn, const u16* __restrict__ Wc,
                                                  const u16* __restrict__ Vc,
                                                  const void* Wq, const void* Wk, const void* Wv,
                                                  const int* __restrict__ flagp,
                                                  u16* __restrict__ Q, u16* __restrict__ K, u16* __restrict__ Vt) {
    __shared__ alignas(16) u16 As[128 * 32];
    __shared__ alignas(16) u16 Bs[128 * 32];
    const int z = blockIdx.z;
    const int fp32m = *flagp;
    if (z == 0) {
        const u16* W = fp32m ? Wc : (const u16*)Wq;
        gemm_core<0>(As, Bs, xn, W, Vc, Q, SCLQ);
    } else if (z == 1) {
        const u16* W = fp32m ? (Wc + 1048576) : (const u16*)Wk;
        gemm_core<0>(As, Bs, xn, W, Vc + 1024, K, 1.0f);
    } else {
        const u16* W = fp32m ? (Wc + 2 * 1048576) : (const u16*)Wv;
        gemm_core<1>(As, Bs, xn, W, Vc + 2048, Vt, 1.0f);
    }
}

// ---------------- Output projection GEMM: 512-thread blocks (16 waves/CU) ----
__global__ __launch_bounds__(512) void gemm_out_k(const u16* __restrict__ Z, const u16* __restrict__ Wc,
                                                  const u16* __restrict__ Vc, const void* Wo,
                                                  u16* __restrict__ out, const int* __restrict__ flagp) {
    __shared__ alignas(16) u16 As[128 * 32];
    __shared__ alignas(16) u16 Bs[128 * 32];
    const int fp32m = *flagp;
    const u16* W = fp32m ? (Wc + 3 * 1048576) : (const u16*)Wo;
    const u16* bias = Vc + 3 * 1024;
    const int tid = threadIdx.x, wave = tid >> 6, lane = tid & 63;
    const int l4 = lane & 15, q4 = lane >> 4;
    const int bm = blockIdx.x, bn = blockIdx.y;
    const int wm = (wave >> 2) * 64, wn = (wave & 3) * 32;
    f32x4 acc[4][2] = {};
    const int srow = (wave & 3) * 32 + (lane >> 2);
    const int skoff = (lane & 3) * 8;
    const u16* Sg = (wave < 4) ? (Z + ((size_t)(bm * 128 + srow)) * DM + skoff)
                               : (W + ((size_t)(bn * 128 + srow)) * DM + skoff);
    u16* dst0 = (wave < 4) ? (As + (wave & 3) * 1024) : (Bs + (wave & 3) * 1024);

    for (int k0 = 0; k0 < DM; k0 += 32) {
        GLD16(Sg + k0, dst0);
        GLD16(Sg + 16 * DM + k0, dst0 + 512);
        __syncthreads();
        bf16x8 af[4], bfr[2];
#pragma unroll
        for (int t = 0; t < 4; ++t)
            af[t] = ld8(As + (wm + t * 16 + l4) * 32 + q4 * 8);
#pragma unroll
        for (int t = 0; t < 2; ++t)
            bfr[t] = ld8(Bs + (wn + t * 16 + l4) * 32 + q4 * 8);
#pragma unroll
        for (int mt = 0; mt < 4; ++mt)
#pragma unroll
            for (int nt = 0; nt < 2; ++nt)
                acc[mt][nt] = __builtin_amdgcn_mfma_f32_16x16x32_bf16(af[mt], bfr[nt], acc[mt][nt], 0, 0, 0);
        __syncthreads();
    }

#pragma unroll
    for (int nt = 0; nt < 2; ++nt) {
        const int col = bn * 128 + wn + nt * 16 + l4;
        const float bs = bf2f(bias[col]);
#pragma unroll
        for (int mt = 0; mt < 4; ++mt) {
            const int row0 = bm * 128 + wm + mt * 16 + q4 * 4;
            if (fp32m) {
#pragma unroll
                for (int r = 0; r < 4; ++r)
                    ((float*)out)[(size_t)(row0 + r) * DM + col] = acc[mt][nt][r] + bs;
            } else {
#pragma unroll
                for (int r = 0; r < 4; ++r)
                    out[(size_t)(row0 + r) * DM + col] = f2bf(acc[mt][nt][r] + bs);
            }
        }
    }
}

// ---------------- Flash attention: uniform-work blocks ----------------
// One 128-row q-tile = device fn; block runs tiles (15-y) then (y):
// (32-2y) + (2y+2) = 34 chunks for EVERY block (uniform by construction).
// Grid (64,8) = 512 blocks, LDS 34KB -> 2 resident blocks/CU.
// ROUND-7 BUG FIX: o[0] accumulation must be guarded by kv0 <= Q0w+15,
// symmetric to o[1]'s kv0 <= Q0w+31 — otherwise stale P0 (pack skipped via
// `continue`) is re-accumulated with new V tiles (absmax 1.22 failure).
__device__ __forceinline__ void flash_tile(int n, int h, int qb,
                                           const u16* __restrict__ Q,
                                           const u16* __restrict__ K,
                                           const u16* __restrict__ Vt,
                                           u16* __restrict__ Z,
                                           u16* Ks0, u16* Ks1, u16* Vs0, u16* Vs1,
                                           u16* P0, u16* P1) {
    const int tid = threadIdx.x, wave = tid >> 6, lane = tid & 63;
    const int l4 = lane & 15, q4 = lane >> 4;

    const int Q0w = qb * 128 + wave * 32;
    bf16x8 qf[2][2];
#pragma unroll
    for (int qt = 0; qt < 2; ++qt) {
        const u16* Qr = Q + ((size_t)(n * SEQ + Q0w + qt * 16 + l4)) * DM + h * 64 + q4 * 8;
        qf[qt][0] = ld8(Qr);
        qf[qt][1] = ld8(Qr + 32);
    }

    const int srow = lane >> 2, scol = (lane & 3) * 8;
    const u16* Kg = K + ((size_t)(n * SEQ + wave * 16 + srow)) * DM + h * 64 + scol;
    const u16* Vg = Vt + ((size_t)(n * 1024 + h * 64 + wave * 16 + srow)) * SEQ + scol;
    u16* KsD0 = Ks0 + wave * 512;
    u16* KsD1 = Ks1 + wave * 512;
    u16* VsD0 = Vs0 + wave * 512;
    u16* VsD1 = Vs1 + wave * 512;

    f32x4 o[2][4] = {};
    float l_acc[2] = {0.f, 0.f};
    const int nch = 2 * qb + 2;

    for (int c = 0; c < nch; ++c) {
        const int kv0 = c * 64;
        const size_t krow = (size_t)kv0 * DM;
        GLD16(Kg + krow, KsD0);
        GLD16(Kg + krow + 32, KsD1);
        GLD16(Vg + kv0, VsD0);
        GLD16(Vg + kv0 + 32, VsD1);
        __syncthreads();

        bf16x8 a[4][2];
#pragma unroll
        for (int mt = 0; mt < 4; ++mt) {
            a[mt][0] = ld8(Ks0 + (mt * 16 + l4) * 32 + q4 * 8);
            a[mt][1] = ld8(Ks1 + (mt * 16 + l4) * 32 + q4 * 8);
        }
#pragma unroll
        for (int qt = 0; qt < 2; ++qt) {
            const int qbase = Q0w + qt * 16;
            if (kv0 > qbase + 15) continue;   // fully masked tile
            f32x4 st[4];
#pragma unroll
            for (int mt = 0; mt < 4; ++mt) {
                f32x4 zz = {0.f, 0.f, 0.f, 0.f};
                st[mt] = __builtin_amdgcn_mfma_f32_16x16x32_bf16(a[mt][0], qf[qt][0], zz, 0, 0, 0);
                st[mt] = __builtin_amdgcn_mfma_f32_16x16x32_bf16(a[mt][1], qf[qt][1], st[mt], 0, 0, 0);
            }
            u16* P = qt ? P1 : P0;
            float la = l_acc[qt];
            if (kv0 + 63 <= qbase) {
#pragma unroll
                for (int mt = 0; mt < 4; ++mt) {
                    __bf16 pk[4];
#pragma unroll
                    for (int r = 0; r < 4; ++r) {
                        float p = __builtin_amdgcn_exp2f(st[mt][r]);
                        la += p;
                        pk[r] = (__bf16)p;
                    }
                    *(u16x4*)(P + l4 * 72 + mt * 16 + q4 * 4) = *(u16x4*)pk;
                }
            } else {
                const int qg = qbase + l4;
#pragma unroll
                for (int mt = 0; mt < 4; ++mt) {
                    __bf16 pk[4];
#pragma unroll
                    for (int r = 0; r < 4; ++r) {
                        const int kv = kv0 + mt * 16 + q4 * 4 + r;
                        float p = __builtin_amdgcn_exp2f(st[mt][r]);
                        p = (kv > qg) ? 0.f : p;
                        la += p;
                        pk[r] = (__bf16)p;
                    }
                    *(u16x4*)(P + l4 * 72 + mt * 16 + q4 * 4) = *(u16x4*)pk;
                }
            }
            l_acc[qt] = la;
        }
#pragma unroll
        for (int ks = 0; ks < 2; ++ks) {
            bf16x8 vf[4];
#pragma unroll
            for (int nt = 0; nt < 4; ++nt)
                vf[nt] = ld8((ks ? Vs1 : Vs0) + (nt * 16 + l4) * 32 + q4 * 8);
            bf16x8 pf0 = ld8(P0 + l4 * 72 + ks * 32 + q4 * 8);
            bf16x8 pf1 = ld8(P1 + l4 * 72 + ks * 32 + q4 * 8);
#pragma unroll
            for (int nt = 0; nt < 4; ++nt) {
                if (kv0 <= Q0w + 15)
                    o[0][nt] = __builtin_amdgcn_mfma_f32_16x16x32_bf16(pf0, vf[nt], o[0][nt], 0, 0, 0);
                if (kv0 <= Q0w + 31)
                    o[1][nt] = __builtin_amdgcn_mfma_f32_16x16x32_bf16(pf1, vf[nt], o[1][nt], 0, 0, 0);
            }
        }
        __syncthreads();
    }

#pragma unroll
    for (int qt = 0; qt < 2; ++qt) {
        float l = l_acc[qt];
        l += __shfl_xor(l, 16);
        l += __shfl_xor(l, 32);
        float lr[4];
#pragma unroll
        for (int r = 0; r < 4; ++r) lr[r] = 1.f / __shfl(l, q4 * 4 + r);
#pragma unroll
        for (int nt = 0; nt < 4; ++nt) {
            const int col = h * 64 + nt * 16 + l4;
#pragma unroll
            for (int r = 0; r < 4; ++r) {
                const int row = n * SEQ + Q0w + qt * 16 + q4 * 4 + r;
                Z[(size_t)row * DM + col] = f2bf(o[qt][nt][r] * lr[r]);
            }
        }
    }
}

__global__ __launch_bounds__(256, 2) void flash_k(const u16* __restrict__ Q,
                                                  const u16* __restrict__ K,
                                                  const u16* __restrict__ Vt,
                                                  u16* __restrict__ Z) {
    const int bh = blockIdx.x, y = blockIdx.y;
    const int n = bh >> 4, h = bh & 15;
    const int wave = threadIdx.x >> 6;

    __shared__ alignas(16) u16 Ks[2][64 * 32];
    __shared__ alignas(16) u16 Vs[2][64 * 32];
    __shared__ alignas(16) u16 Pl[4][2][16 * 72];

    flash_tile(n, h, 15 - y, Q, K, Vt, Z, Ks[0], Ks[1], Vs[0], Vs[1], Pl[wave][0], Pl[wave][1]);
    flash_tile(n, h, y,      Q, K, Vt, Z, Ks[0], Ks[1], Vs[0], Vs[1], Pl[wave][0], Pl[wave][1]);
}

extern "C" void kernel_launch(void* const* d_in, const int* in_sizes, int n_in,
                              void* d_out, int out_size, void* d_ws, size_t ws_size,
                              hipStream_t stream) {
    const void* x  = d_in[0];
    const void* Wq = d_in[1];
    const void* bq = d_in[2];
    const void* Wk = d_in[3];
    const void* bk = d_in[4];
    const void* Wv = d_in[5];
    const void* bv = d_in[6];
    const void* Wo = d_in[7];
    const void* bo = d_in[8];
    const void* g  = d_in[9];
    const void* b  = d_in[10];
    u16* ws = (u16*)d_ws;

    u16* xn  = ws;
    u16* Qb  = ws + (size_t)TOKS;
    u16* Kb  = ws + (size_t)2 * TOKS;
    u16* Vtb = ws + (size_t)3 * TOKS;
    u16* Zb  = ws;  // xn dead after qkv gemm
    u16* Wc  = ws + (size_t)4 * TOKS;
    u16* Vc  = Wc + 4 * 1048576;
    int* flagp = (int*)(Vc + 8 * 1024);

    prep_k<<<dim3(12289), 256, 0, stream>>>(x, Wq, Wk, Wv, Wo, bq, bk, bv, bo, g, b, Wc, Vc, xn, flagp);
    gemm_qkv_k<<<dim3(64, 8, 3), 256, 0, stream>>>(xn, Wc, Vc, Wq, Wk, Wv, flagp, Qb, Kb, Vtb);
    flash_k<<<dim3(64, 8), 256, 0, stream>>>(Qb, Kb, Vtb, Zb);
    gemm_out_k<<<dim3(64, 8), 512, 0, stream>>>(Zb, Wc, Vc, Wo, (u16*)d_out, flagp);
}